// Round 1
// baseline (6678.614 us; speedup 1.0000x reference)
//
#include <hip/hip_runtime.h>
#include <math.h>

#define N_ 2048
#define NF_IN 64
#define D_ 256
#define H_ 8
#define HD_ 32
#define L_ 6
#define FFN_ 1024
#define E_ 32768
#define EF_ 16
#define NF 2049      // N+1 tokens (CLS at row 0)
#define MAXDEG_ 64

__device__ inline float wred_sum(float v){
  #pragma unroll
  for (int o = 32; o > 0; o >>= 1) v += __shfl_down(v, o, 64);
  return v;
}
__device__ inline float wred_max(float v){
  #pragma unroll
  for (int o = 32; o > 0; o >>= 1) v = fmaxf(v, __shfl_down(v, o, 64));
  return v;
}

__global__ void zero_int(int* p, int n){
  int i = blockIdx.x * blockDim.x + threadIdx.x;
  if (i < n) p[i] = 0;
}

__global__ void deg_count(const int* __restrict__ ei, int* __restrict__ ind,
                          int* __restrict__ outd){
  int e = blockIdx.x * blockDim.x + threadIdx.x;
  if (e >= E_) return;
  atomicAdd(&outd[ei[e]], 1);        // out-degree: src = edge_index[0]
  atomicAdd(&ind[ei[E_ + e]], 1);    // in-degree:  dst = edge_index[1]
}

// h[0] = cls; h[1+n] = x[n] @ W^T + b + in_emb + out_emb
__global__ void embed_k(const float* __restrict__ x, const float* __restrict__ W,
                        const float* __restrict__ b, const float* __restrict__ inE,
                        const float* __restrict__ outE, const int* __restrict__ ind,
                        const int* __restrict__ outd, const float* __restrict__ cls,
                        float* __restrict__ h){
  int i = blockIdx.x, d = threadIdx.x;
  if (i == 0){ h[d] = cls[d]; return; }
  int n = i - 1;
  const float4* xr = (const float4*)(x + (long)n * NF_IN);
  const float4* wr = (const float4*)(W + (long)d * NF_IN);
  float acc = b[d];
  #pragma unroll
  for (int k = 0; k < NF_IN / 4; k++){
    float4 a = xr[k], w = wr[k];
    acc += a.x * w.x + a.y * w.y + a.z * w.z + a.w * w.w;
  }
  int id = min(ind[n], MAXDEG_), od = min(outd[n], MAXDEG_);
  acc += inE[(long)id * D_ + d] + outE[(long)od * D_ + d];
  h[(long)i * D_ + d] = acc;
}

// bias[h][i][j] = dist_bias[dist_p[i][j]][h]   (fp32, H planes of Nf x Nf)
__global__ void bias_fill(const int* __restrict__ dist, const float* __restrict__ db,
                          float* __restrict__ bias){
  long idx = (long)blockIdx.x * blockDim.x + threadIdx.x;
  long tot = (long)NF * NF;
  if (idx >= tot) return;
  int i = (int)(idx / NF), j = (int)(idx - (long)i * NF);
  int dp = 0;
  if (i > 0 && j > 0){
    int dv = dist[(long)(i - 1) * N_ + (j - 1)];
    dp = max(0, min(dv, 9));
  }
  #pragma unroll
  for (int h = 0; h < H_; h++)
    bias[((long)h * NF + i) * NF + j] = db[dp * H_ + h];
}

// scatter-add projected edge features (atomic: random edges can collide)
__global__ void edge_bias(const float* __restrict__ ea, const float* __restrict__ W,
                          const float* __restrict__ b, const int* __restrict__ ei,
                          float* __restrict__ bias){
  int e = blockIdx.x * blockDim.x + threadIdx.x;
  if (e >= E_) return;
  float a[EF_];
  #pragma unroll
  for (int k = 0; k < EF_; k++) a[k] = ea[(long)e * EF_ + k];
  int src = ei[e], dst = ei[E_ + e];
  long base = (long)(src + 1) * NF + (dst + 1);
  #pragma unroll
  for (int h = 0; h < H_; h++){
    float p = b[h];
    #pragma unroll
    for (int k = 0; k < EF_; k++) p += a[k] * W[h * EF_ + k];
    atomicAdd(&bias[(long)h * NF * NF + base], p);
  }
}

// LayerNorm over D=256; one block per row, 256 threads
__global__ void ln_k(const float* __restrict__ in, const float* __restrict__ s,
                     const float* __restrict__ b, float* __restrict__ out, int dup0){
  __shared__ float r1[4], r2[4];
  int i = blockIdx.x, d = threadIdx.x;
  float v = in[(long)i * D_ + d];
  float s1 = wred_sum(v), s2 = wred_sum(v * v);
  if ((d & 63) == 0){ r1[d >> 6] = s1; r2[d >> 6] = s2; }
  __syncthreads();
  float S1 = r1[0] + r1[1] + r1[2] + r1[3];
  float S2 = r2[0] + r2[1] + r2[2] + r2[3];
  float m = S1 * (1.0f / D_);
  float var = S2 * (1.0f / D_) - m * m;
  float y = (v - m) * rsqrtf(var + 1e-5f) * s[d] + b[d];
  out[(long)i * D_ + d] = y;
  if (dup0 && i == 0) out[(long)NF * D_ + d] = y;
}

// C[m][n] = act(dot(A[m,:], W[n,:]) + bs[n]) (+ R[m][n])
// A: (M,K) row-major; W: (Nn,K) row-major (i.e. B^T GEMM). ACT: 0=none, 1=gelu(exact)
template<int ACT>
__global__ __launch_bounds__(256) void gemm_k(const float* __restrict__ A,
                     const float* __restrict__ W, const float* __restrict__ bs,
                     const float* __restrict__ R, float* __restrict__ C,
                     int M, int Nn, int K){
  const int BM = 64, BN = 64, BK = 16;
  __shared__ float As[BM][BK + 4], Ws[BN][BK + 4];
  int tid = threadIdx.x;
  int bm = blockIdx.x * BM, bn = blockIdx.y * BN;
  int tx = tid & 15, ty = tid >> 4;
  float acc[4][4] = {};
  int lr = tid >> 2, lc = (tid & 3) * 4;
  for (int k0 = 0; k0 < K; k0 += BK){
    float4 av = make_float4(0, 0, 0, 0);
    int gm = bm + lr;
    if (gm < M) av = *(const float4*)(A + (long)gm * K + k0 + lc);
    *(float4*)&As[lr][lc] = av;
    float4 wv = make_float4(0, 0, 0, 0);
    int gn = bn + lr;
    if (gn < Nn) wv = *(const float4*)(W + (long)gn * K + k0 + lc);
    *(float4*)&Ws[lr][lc] = wv;
    __syncthreads();
    #pragma unroll
    for (int kk = 0; kk < BK; kk++){
      float a0 = As[ty][kk], a1 = As[ty + 16][kk], a2 = As[ty + 32][kk], a3 = As[ty + 48][kk];
      float w0 = Ws[tx][kk], w1 = Ws[tx + 16][kk], w2 = Ws[tx + 32][kk], w3 = Ws[tx + 48][kk];
      acc[0][0] += a0 * w0; acc[0][1] += a0 * w1; acc[0][2] += a0 * w2; acc[0][3] += a0 * w3;
      acc[1][0] += a1 * w0; acc[1][1] += a1 * w1; acc[1][2] += a1 * w2; acc[1][3] += a1 * w3;
      acc[2][0] += a2 * w0; acc[2][1] += a2 * w1; acc[2][2] += a2 * w2; acc[2][3] += a2 * w3;
      acc[3][0] += a3 * w0; acc[3][1] += a3 * w1; acc[3][2] += a3 * w2; acc[3][3] += a3 * w3;
    }
    __syncthreads();
  }
  #pragma unroll
  for (int ii = 0; ii < 4; ii++){
    int gm = bm + ii * 16 + ty;
    if (gm >= M) continue;
    #pragma unroll
    for (int jj = 0; jj < 4; jj++){
      int gn = bn + jj * 16 + tx;
      float v = acc[ii][jj] + bs[gn];
      if (ACT == 1) v = v * 0.5f * (1.0f + erff(v * 0.70710678118654752f));
      if (R) v += R[(long)gm * Nn + gn];
      C[(long)gm * Nn + gn] = v;
    }
  }
}

// one block per (query row i, head h): logits row in LDS -> softmax -> P@V
__global__ __launch_bounds__(256) void attn_k(const float* __restrict__ Q,
                      const float* __restrict__ Km, const float* __restrict__ Vm,
                      const float* __restrict__ bias, float* __restrict__ O){
  __shared__ float p[NF];
  __shared__ float qs[HD_];
  __shared__ float redm[4], reds[4];
  __shared__ float oacc[8][HD_];
  int i = blockIdx.x, h = blockIdx.y, tid = threadIdx.x;
  if (tid < HD_) qs[tid] = Q[(long)i * D_ + h * HD_ + tid];
  __syncthreads();
  const float scale = 0.17677669529663687f;  // 1/sqrt(32)
  const float* brow = bias + ((long)h * NF + i) * NF;
  float lmax = -1e30f;
  for (int j = tid; j < NF; j += 256){
    const float4* kr = (const float4*)(Km + (long)j * D_ + h * HD_);
    const float4* q4 = (const float4*)qs;
    float acc = 0.f;
    #pragma unroll
    for (int k = 0; k < HD_ / 4; k++){
      float4 a = q4[k], kk = kr[k];
      acc += a.x * kk.x + a.y * kk.y + a.z * kk.z + a.w * kk.w;
    }
    float l = acc * scale + brow[j];
    p[j] = l;
    lmax = fmaxf(lmax, l);
  }
  lmax = wred_max(lmax);
  if ((tid & 63) == 0) redm[tid >> 6] = lmax;
  __syncthreads();
  float bmax = fmaxf(fmaxf(redm[0], redm[1]), fmaxf(redm[2], redm[3]));
  float lsum = 0.f;
  for (int j = tid; j < NF; j += 256){
    float e = __expf(p[j] - bmax);
    p[j] = e;
    lsum += e;
  }
  lsum = wred_sum(lsum);
  if ((tid & 63) == 0) reds[tid >> 6] = lsum;
  __syncthreads();
  float bsum = reds[0] + reds[1] + reds[2] + reds[3];
  int d = tid & (HD_ - 1), g = tid >> 5;  // 8 j-groups x 32 dims
  float a = 0.f;
  for (int j = g; j < NF; j += 8) a += p[j] * Vm[(long)j * D_ + h * HD_ + d];
  oacc[g][d] = a;
  __syncthreads();
  if (tid < HD_){
    float s = 0.f;
    #pragma unroll
    for (int g2 = 0; g2 < 8; g2++) s += oacc[g2][tid];
    O[(long)i * D_ + h * HD_ + tid] = s / bsum;
  }
}

extern "C" void kernel_launch(void* const* d_in, const int* in_sizes, int n_in,
                              void* d_out, int out_size, void* d_ws, size_t ws_size,
                              hipStream_t stream){
  const float* x    = (const float*)d_in[0];
  const float* ea   = (const float*)d_in[1];
  const float* npw  = (const float*)d_in[2];
  const float* npb  = (const float*)d_in[3];
  const float* inE  = (const float*)d_in[4];
  const float* outE = (const float*)d_in[5];
  const float* db   = (const float*)d_in[6];
  const float* epw  = (const float*)d_in[7];
  const float* epb  = (const float*)d_in[8];
  const float* cls  = (const float*)d_in[9];
  const float* qw   = (const float*)d_in[10];
  const float* qb   = (const float*)d_in[11];
  const float* kw   = (const float*)d_in[12];
  const float* kb   = (const float*)d_in[13];
  const float* vw   = (const float*)d_in[14];
  const float* vb   = (const float*)d_in[15];
  const float* ow   = (const float*)d_in[16];
  const float* ob   = (const float*)d_in[17];
  const float* f1w  = (const float*)d_in[18];
  const float* f1b  = (const float*)d_in[19];
  const float* f2w  = (const float*)d_in[20];
  const float* f2b  = (const float*)d_in[21];
  const float* ln1s = (const float*)d_in[22];
  const float* ln1b = (const float*)d_in[23];
  const float* ln2s = (const float*)d_in[24];
  const float* ln2b = (const float*)d_in[25];
  const float* fns  = (const float*)d_in[26];
  const float* fnb  = (const float*)d_in[27];
  const int*   ei   = (const int*)d_in[28];
  const int*   dist = (const int*)d_in[29];

  float* ws = (float*)d_ws;
  long off = 0;
  float* bias = ws + off; off += (long)H_ * NF * NF;   // 33,587,208
  float* h    = ws + off; off += (long)NF * D_;
  float* hn   = ws + off; off += (long)NF * D_;
  float* Qm   = ws + off; off += (long)NF * D_;
  float* Km   = ws + off; off += (long)NF * D_;
  float* Vm   = ws + off; off += (long)NF * D_;
  float* om   = ws + off; off += (long)NF * D_;
  float* mid  = ws + off; off += (long)NF * FFN_;
  int* ind  = (int*)(ws + off);
  int* outd = ind + N_;

  zero_int<<<(2 * N_ + 255) / 256, 256, 0, stream>>>(ind, 2 * N_);
  deg_count<<<(E_ + 255) / 256, 256, 0, stream>>>(ei, ind, outd);
  embed_k<<<NF, D_, 0, stream>>>(x, npw, npb, inE, outE, ind, outd, cls, h);
  long tot = (long)NF * NF;
  bias_fill<<<(int)((tot + 255) / 256), 256, 0, stream>>>(dist, db, bias);
  edge_bias<<<(E_ + 255) / 256, 256, 0, stream>>>(ea, epw, epb, ei, bias);

  dim3 gD((NF + 63) / 64, D_ / 64);
  dim3 gF((NF + 63) / 64, FFN_ / 64);
  for (int l = 0; l < L_; l++){
    ln_k<<<NF, D_, 0, stream>>>(h, ln1s + l * D_, ln1b + l * D_, hn, 0);
    gemm_k<0><<<gD, 256, 0, stream>>>(hn, qw + (long)l * D_ * D_, qb + l * D_, nullptr, Qm, NF, D_, D_);
    gemm_k<0><<<gD, 256, 0, stream>>>(hn, kw + (long)l * D_ * D_, kb + l * D_, nullptr, Km, NF, D_, D_);
    gemm_k<0><<<gD, 256, 0, stream>>>(hn, vw + (long)l * D_ * D_, vb + l * D_, nullptr, Vm, NF, D_, D_);
    attn_k<<<dim3(NF, H_), 256, 0, stream>>>(Qm, Km, Vm, bias, om);
    gemm_k<0><<<gD, 256, 0, stream>>>(om, ow + (long)l * D_ * D_, ob + l * D_, h, h, NF, D_, D_);
    ln_k<<<NF, D_, 0, stream>>>(h, ln2s + l * D_, ln2b + l * D_, hn, 0);
    gemm_k<1><<<gF, 256, 0, stream>>>(hn, f1w + (long)l * FFN_ * D_, f1b + l * FFN_, nullptr, mid, NF, FFN_, D_);
    gemm_k<0><<<gD, 256, 0, stream>>>(mid, f2w + (long)l * D_ * FFN_, f2b + l * D_, h, h, NF, D_, FFN_);
  }
  ln_k<<<NF, D_, 0, stream>>>(h, fns, fnb, (float*)d_out, 1);
}

// Round 2
// 3175.554 us; speedup vs baseline: 2.1031x; 2.1031x over previous
//
#include <hip/hip_runtime.h>
#include <math.h>

#define N_ 2048
#define NF_IN 64
#define D_ 256
#define H_ 8
#define HD_ 32
#define L_ 6
#define FFN_ 1024
#define E_ 32768
#define EF_ 16
#define NF 2049      // N+1 tokens (CLS at row 0)
#define MAXDEG_ 64
#define KT 64        // keys per flash tile

typedef __attribute__((ext_vector_type(8))) short bf16x8;
typedef __attribute__((ext_vector_type(4))) float f32x4;

__device__ inline unsigned short f2b(float f){
  union { float f; unsigned u; } v; v.f = f;
  unsigned r = (v.u + 0x7fffu + ((v.u >> 16) & 1u)) >> 16;
  return (unsigned short)r;
}

__device__ inline float wred_sum(float v){
  #pragma unroll
  for (int o = 32; o > 0; o >>= 1) v += __shfl_down(v, o, 64);
  return v;
}

__global__ void zero_int(int* p, int n){
  int i = blockIdx.x * blockDim.x + threadIdx.x;
  if (i < n) p[i] = 0;
}

__global__ void deg_count(const int* __restrict__ ei, int* __restrict__ ind,
                          int* __restrict__ outd){
  int e = blockIdx.x * blockDim.x + threadIdx.x;
  if (e >= E_) return;
  atomicAdd(&outd[ei[e]], 1);
  atomicAdd(&ind[ei[E_ + e]], 1);
}

__global__ void embed_k(const float* __restrict__ x, const float* __restrict__ W,
                        const float* __restrict__ b, const float* __restrict__ inE,
                        const float* __restrict__ outE, const int* __restrict__ ind,
                        const int* __restrict__ outd, const float* __restrict__ cls,
                        float* __restrict__ h){
  int i = blockIdx.x, d = threadIdx.x;
  if (i == 0){ h[d] = cls[d]; return; }
  int n = i - 1;
  const float4* xr = (const float4*)(x + (long)n * NF_IN);
  const float4* wr = (const float4*)(W + (long)d * NF_IN);
  float acc = b[d];
  #pragma unroll
  for (int k = 0; k < NF_IN / 4; k++){
    float4 a = xr[k], w = wr[k];
    acc += a.x * w.x + a.y * w.y + a.z * w.z + a.w * w.w;
  }
  int id = min(ind[n], MAXDEG_), od = min(outd[n], MAXDEG_);
  acc += inE[(long)id * D_ + d] + outE[(long)od * D_ + d];
  h[(long)i * D_ + d] = acc;
}

__global__ void bias_fill(const int* __restrict__ dist, const float* __restrict__ db,
                          float* __restrict__ bias){
  long idx = (long)blockIdx.x * blockDim.x + threadIdx.x;
  long tot = (long)NF * NF;
  if (idx >= tot) return;
  int i = (int)(idx / NF), j = (int)(idx - (long)i * NF);
  int dp = 0;
  if (i > 0 && j > 0){
    int dv = dist[(long)(i - 1) * N_ + (j - 1)];
    dp = max(0, min(dv, 9));
  }
  #pragma unroll
  for (int h = 0; h < H_; h++)
    bias[((long)h * NF + i) * NF + j] = db[dp * H_ + h];
}

__global__ void edge_bias(const float* __restrict__ ea, const float* __restrict__ W,
                          const float* __restrict__ b, const int* __restrict__ ei,
                          float* __restrict__ bias){
  int e = blockIdx.x * blockDim.x + threadIdx.x;
  if (e >= E_) return;
  float a[EF_];
  #pragma unroll
  for (int k = 0; k < EF_; k++) a[k] = ea[(long)e * EF_ + k];
  int src = ei[e], dst = ei[E_ + e];
  long base = (long)(src + 1) * NF + (dst + 1);
  #pragma unroll
  for (int h = 0; h < H_; h++){
    float p = b[h];
    #pragma unroll
    for (int k = 0; k < EF_; k++) p += a[k] * W[h * EF_ + k];
    atomicAdd(&bias[(long)h * NF * NF + base], p);
  }
}

__global__ void ln_k(const float* __restrict__ in, const float* __restrict__ s,
                     const float* __restrict__ b, float* __restrict__ out, int dup0){
  __shared__ float r1[4], r2[4];
  int i = blockIdx.x, d = threadIdx.x;
  float v = in[(long)i * D_ + d];
  float s1 = wred_sum(v), s2 = wred_sum(v * v);
  if ((d & 63) == 0){ r1[d >> 6] = s1; r2[d >> 6] = s2; }
  __syncthreads();
  float S1 = r1[0] + r1[1] + r1[2] + r1[3];
  float S2 = r2[0] + r2[1] + r2[2] + r2[3];
  float m = S1 * (1.0f / D_);
  float var = S2 * (1.0f / D_) - m * m;
  float y = (v - m) * rsqrtf(var + 1e-5f) * s[d] + b[d];
  out[(long)i * D_ + d] = y;
  if (dup0 && i == 0) out[(long)NF * D_ + d] = y;
}

template<int ACT>
__global__ __launch_bounds__(256) void gemm_k(const float* __restrict__ A,
                     const float* __restrict__ W, const float* __restrict__ bs,
                     const float* __restrict__ R, float* __restrict__ C,
                     int M, int Nn, int K){
  const int BM = 64, BN = 64, BK = 16;
  __shared__ float As[BM][BK + 4], Ws[BN][BK + 4];
  int tid = threadIdx.x;
  int bm = blockIdx.x * BM, bn = blockIdx.y * BN;
  int tx = tid & 15, ty = tid >> 4;
  float acc[4][4] = {};
  int lr = tid >> 2, lc = (tid & 3) * 4;
  for (int k0 = 0; k0 < K; k0 += BK){
    float4 av = make_float4(0, 0, 0, 0);
    int gm = bm + lr;
    if (gm < M) av = *(const float4*)(A + (long)gm * K + k0 + lc);
    *(float4*)&As[lr][lc] = av;
    float4 wv = make_float4(0, 0, 0, 0);
    int gn = bn + lr;
    if (gn < Nn) wv = *(const float4*)(W + (long)gn * K + k0 + lc);
    *(float4*)&Ws[lr][lc] = wv;
    __syncthreads();
    #pragma unroll
    for (int kk = 0; kk < BK; kk++){
      float a0 = As[ty][kk], a1 = As[ty + 16][kk], a2 = As[ty + 32][kk], a3 = As[ty + 48][kk];
      float w0 = Ws[tx][kk], w1 = Ws[tx + 16][kk], w2 = Ws[tx + 32][kk], w3 = Ws[tx + 48][kk];
      acc[0][0] += a0 * w0; acc[0][1] += a0 * w1; acc[0][2] += a0 * w2; acc[0][3] += a0 * w3;
      acc[1][0] += a1 * w0; acc[1][1] += a1 * w1; acc[1][2] += a1 * w2; acc[1][3] += a1 * w3;
      acc[2][0] += a2 * w0; acc[2][1] += a2 * w1; acc[2][2] += a2 * w2; acc[2][3] += a2 * w3;
      acc[3][0] += a3 * w0; acc[3][1] += a3 * w1; acc[3][2] += a3 * w2; acc[3][3] += a3 * w3;
    }
    __syncthreads();
  }
  #pragma unroll
  for (int ii = 0; ii < 4; ii++){
    int gm = bm + ii * 16 + ty;
    if (gm >= M) continue;
    #pragma unroll
    for (int jj = 0; jj < 4; jj++){
      int gn = bn + jj * 16 + tx;
      float v = acc[ii][jj] + bs[gn];
      if (ACT == 1) v = v * 0.5f * (1.0f + erff(v * 0.70710678118654752f));
      if (R) v += R[(long)gm * Nn + gn];
      C[(long)gm * Nn + gn] = v;
    }
  }
}

// Flash attention: block = 2 waves; each wave owns 16 query rows of head blockIdx.y.
// K tile staged row-major bf16 (B-frag of QK^T reads K rows contiguously);
// V tile staged transposed (B-frag of PV reads V columns contiguously);
// P converted C-layout -> A-layout through per-wave LDS buffer.
__global__ __launch_bounds__(128) void fattn_k(const float* __restrict__ Q,
                      const float* __restrict__ Km, const float* __restrict__ Vm,
                      const float* __restrict__ bias, float* __restrict__ O){
  __shared__ __align__(16) short Ks[KT][40];     // [key][dim], pad to 80B rows
  __shared__ __align__(16) short Vt[HD_][80];    // [dim][key], pad to 160B rows
  __shared__ __align__(16) short Ps[2][16][80];  // per-wave P tile [m][j]

  const int tid = threadIdx.x;
  const int wave = tid >> 6, lane = tid & 63;
  const int col = lane & 15, quad = lane >> 4;
  const int h = blockIdx.y;
  const int i0 = blockIdx.x * 32 + wave * 16;

  // Q fragment: A[m=col][k=quad*8+jj]
  int qrow = min(i0 + col, NF - 1);
  const float* qp = Q + (long)qrow * D_ + h * HD_ + quad * 8;
  float4 qa = *(const float4*)qp;
  float4 qb = *(const float4*)(qp + 4);
  bf16x8 q_frag;
  q_frag[0] = (short)f2b(qa.x); q_frag[1] = (short)f2b(qa.y);
  q_frag[2] = (short)f2b(qa.z); q_frag[3] = (short)f2b(qa.w);
  q_frag[4] = (short)f2b(qb.x); q_frag[5] = (short)f2b(qb.y);
  q_frag[6] = (short)f2b(qb.z); q_frag[7] = (short)f2b(qb.w);

  float mx[4], sm[4];
  f32x4 oacc[2];
  const f32x4 zero4 = {0.f, 0.f, 0.f, 0.f};
  #pragma unroll
  for (int r = 0; r < 4; r++){ mx[r] = -1e30f; sm[r] = 0.f; }
  oacc[0] = zero4; oacc[1] = zero4;

  const float* bh = bias + (long)h * NF * NF;
  const float scale = 0.17677669529663687f;  // 1/sqrt(32)
  const int ntiles = (NF + KT - 1) / KT;     // 33

  for (int jt = 0; jt < ntiles; jt++){
    const int j0 = jt * KT;
    __syncthreads();
    // stage K tile: 64 keys x 32 dims, 512 float4 reads
    #pragma unroll
    for (int q = 0; q < 4; q++){
      int idx = q * 128 + tid;
      int key = idx >> 3, f4 = idx & 7;
      int j = j0 + key;
      float4 v = make_float4(0, 0, 0, 0);
      if (j < NF) v = *(const float4*)(Km + (long)j * D_ + h * HD_ + f4 * 4);
      short4 s;
      s.x = (short)f2b(v.x); s.y = (short)f2b(v.y);
      s.z = (short)f2b(v.z); s.w = (short)f2b(v.w);
      *(short4*)&Ks[key][f4 * 4] = s;
    }
    // stage V tile transposed: item = (dim d, key pair kp)
    #pragma unroll
    for (int q = 0; q < 8; q++){
      int idx = q * 128 + tid;
      int d = idx & 31, kp = idx >> 5;
      int j = j0 + kp * 2;
      float v0 = (j < NF)     ? Vm[(long)j * D_ + h * HD_ + d]       : 0.f;
      float v1 = (j + 1 < NF) ? Vm[(long)(j + 1) * D_ + h * HD_ + d] : 0.f;
      short2 s; s.x = (short)f2b(v0); s.y = (short)f2b(v1);
      *(short2*)&Vt[d][kp * 2] = s;
    }
    __syncthreads();

    // S = Q K^T for 4 sub-tiles of 16 keys
    f32x4 sacc[4];
    #pragma unroll
    for (int t = 0; t < 4; t++){
      bf16x8 kf = *(const bf16x8*)&Ks[t * 16 + col][quad * 8];
      sacc[t] = __builtin_amdgcn_mfma_f32_16x16x32_bf16(q_frag, kf, zero4, 0, 0, 0);
    }

    // logits + bias; C layout: row m = quad*4+r, col n = t*16+col
    float lg[4][4];
    #pragma unroll
    for (int r = 0; r < 4; r++){
      int ig = min(i0 + quad * 4 + r, NF - 1);
      const float* br = bh + (long)ig * NF + j0;
      #pragma unroll
      for (int t = 0; t < 4; t++){
        int j = j0 + t * 16 + col;
        lg[t][r] = (j < NF) ? (sacc[t][r] * scale + br[t * 16 + col]) : -1e30f;
      }
    }

    // online softmax per row
    #pragma unroll
    for (int r = 0; r < 4; r++){
      float tm = fmaxf(fmaxf(lg[0][r], lg[1][r]), fmaxf(lg[2][r], lg[3][r]));
      #pragma unroll
      for (int o = 1; o < 16; o <<= 1) tm = fmaxf(tm, __shfl_xor(tm, o, 64));
      float nm = fmaxf(mx[r], tm);
      float al = __expf(mx[r] - nm);
      mx[r] = nm;
      float rs = 0.f;
      #pragma unroll
      for (int t = 0; t < 4; t++){
        float p = __expf(lg[t][r] - nm);
        lg[t][r] = p;
        rs += p;
      }
      #pragma unroll
      for (int o = 1; o < 16; o <<= 1) rs += __shfl_xor(rs, o, 64);
      sm[r] = sm[r] * al + rs;
      oacc[0][r] *= al;
      oacc[1][r] *= al;
    }

    // write P (C layout) to LDS as bf16
    #pragma unroll
    for (int r = 0; r < 4; r++)
      #pragma unroll
      for (int t = 0; t < 4; t++)
        Ps[wave][quad * 4 + r][t * 16 + col] = (short)f2b(lg[t][r]);

    // PV: A = P (16 x 64), B = V (64 x 32)
    #pragma unroll
    for (int ks = 0; ks < 2; ks++){
      bf16x8 af = *(const bf16x8*)&Ps[wave][col][ks * 32 + quad * 8];
      #pragma unroll
      for (int dt = 0; dt < 2; dt++){
        bf16x8 vf = *(const bf16x8*)&Vt[dt * 16 + col][ks * 32 + quad * 8];
        oacc[dt] = __builtin_amdgcn_mfma_f32_16x16x32_bf16(af, vf, oacc[dt], 0, 0, 0);
      }
    }
  }

  // epilogue: O[m][d] = oacc/sm
  #pragma unroll
  for (int r = 0; r < 4; r++){
    int ig = i0 + quad * 4 + r;
    if (ig >= NF) continue;
    float inv = 1.0f / sm[r];
    #pragma unroll
    for (int dt = 0; dt < 2; dt++)
      O[(long)ig * D_ + h * HD_ + dt * 16 + col] = oacc[dt][r] * inv;
  }
}

extern "C" void kernel_launch(void* const* d_in, const int* in_sizes, int n_in,
                              void* d_out, int out_size, void* d_ws, size_t ws_size,
                              hipStream_t stream){
  const float* x    = (const float*)d_in[0];
  const float* ea   = (const float*)d_in[1];
  const float* npw  = (const float*)d_in[2];
  const float* npb  = (const float*)d_in[3];
  const float* inE  = (const float*)d_in[4];
  const float* outE = (const float*)d_in[5];
  const float* db   = (const float*)d_in[6];
  const float* epw  = (const float*)d_in[7];
  const float* epb  = (const float*)d_in[8];
  const float* cls  = (const float*)d_in[9];
  const float* qw   = (const float*)d_in[10];
  const float* qb   = (const float*)d_in[11];
  const float* kw   = (const float*)d_in[12];
  const float* kb   = (const float*)d_in[13];
  const float* vw   = (const float*)d_in[14];
  const float* vb   = (const float*)d_in[15];
  const float* ow   = (const float*)d_in[16];
  const float* ob   = (const float*)d_in[17];
  const float* f1w  = (const float*)d_in[18];
  const float* f1b  = (const float*)d_in[19];
  const float* f2w  = (const float*)d_in[20];
  const float* f2b_ = (const float*)d_in[21];
  const float* ln1s = (const float*)d_in[22];
  const float* ln1b = (const float*)d_in[23];
  const float* ln2s = (const float*)d_in[24];
  const float* ln2b = (const float*)d_in[25];
  const float* fns  = (const float*)d_in[26];
  const float* fnb  = (const float*)d_in[27];
  const int*   ei   = (const int*)d_in[28];
  const int*   dist = (const int*)d_in[29];

  float* ws = (float*)d_ws;
  long off = 0;
  float* bias = ws + off; off += (long)H_ * NF * NF;
  float* h    = ws + off; off += (long)NF * D_;
  float* hn   = ws + off; off += (long)NF * D_;
  float* Qm   = ws + off; off += (long)NF * D_;
  float* Km   = ws + off; off += (long)NF * D_;
  float* Vm   = ws + off; off += (long)NF * D_;
  float* om   = ws + off; off += (long)NF * D_;
  float* mid  = ws + off; off += (long)NF * FFN_;
  int* ind  = (int*)(ws + off);
  int* outd = ind + N_;

  zero_int<<<(2 * N_ + 255) / 256, 256, 0, stream>>>(ind, 2 * N_);
  deg_count<<<(E_ + 255) / 256, 256, 0, stream>>>(ei, ind, outd);
  embed_k<<<NF, D_, 0, stream>>>(x, npw, npb, inE, outE, ind, outd, cls, h);
  long tot = (long)NF * NF;
  bias_fill<<<(int)((tot + 255) / 256), 256, 0, stream>>>(dist, db, bias);
  edge_bias<<<(E_ + 255) / 256, 256, 0, stream>>>(ea, epw, epb, ei, bias);

  dim3 gD((NF + 63) / 64, D_ / 64);
  dim3 gF((NF + 63) / 64, FFN_ / 64);
  dim3 gA((NF + 31) / 32, H_);
  for (int l = 0; l < L_; l++){
    ln_k<<<NF, D_, 0, stream>>>(h, ln1s + l * D_, ln1b + l * D_, hn, 0);
    gemm_k<0><<<gD, 256, 0, stream>>>(hn, qw + (long)l * D_ * D_, qb + l * D_, nullptr, Qm, NF, D_, D_);
    gemm_k<0><<<gD, 256, 0, stream>>>(hn, kw + (long)l * D_ * D_, kb + l * D_, nullptr, Km, NF, D_, D_);
    gemm_k<0><<<gD, 256, 0, stream>>>(hn, vw + (long)l * D_ * D_, vb + l * D_, nullptr, Vm, NF, D_, D_);
    fattn_k<<<gA, 128, 0, stream>>>(Qm, Km, Vm, bias, om);
    gemm_k<0><<<gD, 256, 0, stream>>>(om, ow + (long)l * D_ * D_, ob + l * D_, h, h, NF, D_, D_);
    ln_k<<<NF, D_, 0, stream>>>(h, ln2s + l * D_, ln2b + l * D_, hn, 0);
    gemm_k<1><<<gF, 256, 0, stream>>>(hn, f1w + (long)l * FFN_ * D_, f1b + l * FFN_, nullptr, mid, NF, FFN_, D_);
    gemm_k<0><<<gD, 256, 0, stream>>>(mid, f2w + (long)l * D_ * FFN_, f2b_ + l * D_, h, h, NF, D_, FFN_);
  }
  ln_k<<<NF, D_, 0, stream>>>(h, fns, fnb, (float*)d_out, 1);
}

// Round 3
// 951.291 us; speedup vs baseline: 7.0206x; 3.3382x over previous
//
#include <hip/hip_runtime.h>
#include <math.h>

#define N_ 2048
#define NF_IN 64
#define D_ 256
#define H_ 8
#define HD_ 32
#define L_ 6
#define FFN_ 1024
#define E_ 32768
#define EF_ 16
#define NF 2049      // N+1 tokens (CLS at row 0)
#define MAXDEG_ 64
#define BSTRIDE 2064 // padded bias/Vt row stride (multiple of 8 -> 16B aligned)
#define RPAD 2080    // padded row count for attention partials (65*32)

typedef __attribute__((ext_vector_type(8))) short bf16x8;
typedef __attribute__((ext_vector_type(4))) float f32x4;

__device__ inline unsigned short f2b(float f){
  union { float f; unsigned u; } v; v.f = f;
  unsigned r = (v.u + 0x7fffu + ((v.u >> 16) & 1u)) >> 16;
  return (unsigned short)r;
}
__device__ inline float b2f(short s){
  union { unsigned u; float f; } v; v.u = ((unsigned)(unsigned short)s) << 16;
  return v.f;
}

__device__ inline float wred_sum(float v){
  #pragma unroll
  for (int o = 32; o > 0; o >>= 1) v += __shfl_down(v, o, 64);
  return v;
}

__global__ void zero_int(int* p, int n){
  int i = blockIdx.x * blockDim.x + threadIdx.x;
  if (i < n) p[i] = 0;
}

__global__ void deg_count(const int* __restrict__ ei, int* __restrict__ ind,
                          int* __restrict__ outd){
  int e = blockIdx.x * blockDim.x + threadIdx.x;
  if (e >= E_) return;
  atomicAdd(&outd[ei[e]], 1);
  atomicAdd(&ind[ei[E_ + e]], 1);
}

__global__ void embed_k(const float* __restrict__ x, const float* __restrict__ W,
                        const float* __restrict__ b, const float* __restrict__ inE,
                        const float* __restrict__ outE, const int* __restrict__ ind,
                        const int* __restrict__ outd, const float* __restrict__ cls,
                        float* __restrict__ h){
  int i = blockIdx.x, d = threadIdx.x;
  if (i == 0){ h[d] = cls[d]; return; }
  int n = i - 1;
  const float4* xr = (const float4*)(x + (long)n * NF_IN);
  const float4* wr = (const float4*)(W + (long)d * NF_IN);
  float acc = b[d];
  #pragma unroll
  for (int k = 0; k < NF_IN / 4; k++){
    float4 a = xr[k], w = wr[k];
    acc += a.x * w.x + a.y * w.y + a.z * w.z + a.w * w.w;
  }
  int id = min(ind[n], MAXDEG_), od = min(outd[n], MAXDEG_);
  acc += inE[(long)id * D_ + d] + outE[(long)od * D_ + d];
  h[(long)i * D_ + d] = acc;
}

__global__ void bias_fill(const int* __restrict__ dist, const float* __restrict__ db,
                          float* __restrict__ bias){
  long idx = (long)blockIdx.x * blockDim.x + threadIdx.x;
  long tot = (long)NF * NF;
  if (idx >= tot) return;
  int i = (int)(idx / NF), j = (int)(idx - (long)i * NF);
  int dp = 0;
  if (i > 0 && j > 0){
    int dv = dist[(long)(i - 1) * N_ + (j - 1)];
    dp = max(0, min(dv, 9));
  }
  #pragma unroll
  for (int h = 0; h < H_; h++)
    bias[((long)h * NF + i) * NF + j] = db[dp * H_ + h];
}

__global__ void edge_bias(const float* __restrict__ ea, const float* __restrict__ W,
                          const float* __restrict__ b, const int* __restrict__ ei,
                          float* __restrict__ bias){
  int e = blockIdx.x * blockDim.x + threadIdx.x;
  if (e >= E_) return;
  float a[EF_];
  #pragma unroll
  for (int k = 0; k < EF_; k++) a[k] = ea[(long)e * EF_ + k];
  int src = ei[e], dst = ei[E_ + e];
  long base = (long)(src + 1) * NF + (dst + 1);
  #pragma unroll
  for (int h = 0; h < H_; h++){
    float p = b[h];
    #pragma unroll
    for (int k = 0; k < EF_; k++) p += a[k] * W[h * EF_ + k];
    atomicAdd(&bias[(long)h * NF * NF + base], p);
  }
}

// fp32 bias -> padded bf16 bias (row stride BSTRIDE, pad zeroed)
__global__ void bias_cvt(const float* __restrict__ bf, short* __restrict__ bb){
  long row = blockIdx.x;  // H*NF rows
  const float* src = bf + row * NF;
  short* dst = bb + row * BSTRIDE;
  for (int j = threadIdx.x; j < BSTRIDE; j += 256)
    dst[j] = (j < NF) ? (short)f2b(src[j]) : (short)0;
}

// generic fp32 -> bf16 (with optional block-interleave for QKV weights)
__global__ void w2b(const float* __restrict__ src, short* __restrict__ dst,
                    long n, long per, long ostride, long ooff){
  long i = (long)blockIdx.x * 256 + threadIdx.x;
  if (i >= n) return;
  long l = i / per, r = i - l * per;
  dst[l * ostride + ooff + r] = (short)f2b(src[i]);
}

// LayerNorm over D=256; writes fp32 and/or bf16
__global__ void ln_k(const float* __restrict__ in, const float* __restrict__ s,
                     const float* __restrict__ b, float* __restrict__ outf,
                     short* __restrict__ outb, int dup0){
  __shared__ float r1[4], r2[4];
  int i = blockIdx.x, d = threadIdx.x;
  float v = in[(long)i * D_ + d];
  float s1 = wred_sum(v), s2 = wred_sum(v * v);
  if ((d & 63) == 0){ r1[d >> 6] = s1; r2[d >> 6] = s2; }
  __syncthreads();
  float S1 = r1[0] + r1[1] + r1[2] + r1[3];
  float S2 = r2[0] + r2[1] + r2[2] + r2[3];
  float m = S1 * (1.0f / D_);
  float var = S2 * (1.0f / D_) - m * m;
  float y = (v - m) * rsqrtf(var + 1e-5f) * s[d] + b[d];
  if (outf){
    outf[(long)i * D_ + d] = y;
    if (dup0 && i == 0) outf[(long)NF * D_ + d] = y;
  }
  if (outb) outb[(long)i * D_ + d] = (short)f2b(y);
}

// ---- fused QKV MFMA GEMM: grid (33, 4, 3); z selects weight/bias/output ----
__global__ __launch_bounds__(256) void qkv_gemm(const short* __restrict__ A,
    const short* __restrict__ Wall, const float* __restrict__ qb,
    const float* __restrict__ kb, const float* __restrict__ vb,
    short* __restrict__ QKb, short* __restrict__ Vtg, int l){
  const int z = blockIdx.z;
  const short* W = Wall + ((long)(l * 3 + z)) * D_ * D_;
  const float* bsp = (z == 0) ? qb : (z == 1) ? kb : vb;
  __shared__ __align__(16) short As[64][40], Ws[64][40];
  const int tid = threadIdx.x, lane = tid & 63, wave = tid >> 6;
  const int col = lane & 15, quad = lane >> 4;
  const int wm = wave & 1, wn = wave >> 1;
  const int bm = blockIdx.x * 64, bn = blockIdx.y * 64;
  const f32x4 zero4 = {0.f, 0.f, 0.f, 0.f};
  f32x4 acc[2][2] = {{zero4, zero4}, {zero4, zero4}};
  const int row = tid >> 2, seg = tid & 3;
  for (int k0 = 0; k0 < D_; k0 += 32){
    __syncthreads();
    bf16x8 av = (bf16x8)(short)0;
    int gm = bm + row;
    if (gm < NF) av = *(const bf16x8*)(A + (long)gm * D_ + k0 + seg * 8);
    *(bf16x8*)&As[row][seg * 8] = av;
    *(bf16x8*)&Ws[row][seg * 8] = *(const bf16x8*)(W + (long)(bn + row) * D_ + k0 + seg * 8);
    __syncthreads();
    bf16x8 a0 = *(const bf16x8*)&As[wm * 32 + col][quad * 8];
    bf16x8 a1 = *(const bf16x8*)&As[wm * 32 + 16 + col][quad * 8];
    bf16x8 b0 = *(const bf16x8*)&Ws[wn * 32 + col][quad * 8];
    bf16x8 b1 = *(const bf16x8*)&Ws[wn * 32 + 16 + col][quad * 8];
    acc[0][0] = __builtin_amdgcn_mfma_f32_16x16x32_bf16(a0, b0, acc[0][0], 0, 0, 0);
    acc[0][1] = __builtin_amdgcn_mfma_f32_16x16x32_bf16(a0, b1, acc[0][1], 0, 0, 0);
    acc[1][0] = __builtin_amdgcn_mfma_f32_16x16x32_bf16(a1, b0, acc[1][0], 0, 0, 0);
    acc[1][1] = __builtin_amdgcn_mfma_f32_16x16x32_bf16(a1, b1, acc[1][1], 0, 0, 0);
  }
  #pragma unroll
  for (int i = 0; i < 2; i++)
    #pragma unroll
    for (int j = 0; j < 2; j++)
      #pragma unroll
      for (int r = 0; r < 4; r++){
        int gm = bm + wm * 32 + i * 16 + quad * 4 + r;
        if (gm >= NF) continue;
        int gn = bn + wn * 32 + j * 16 + col;
        float v = acc[i][j][r] + bsp[gn];
        if (z < 2) QKb[(long)z * NF * D_ + (long)gm * D_ + gn] = (short)f2b(v);
        else       Vtg[(long)gn * BSTRIDE + gm] = (short)f2b(v);
      }
}

// ---- generic MFMA GEMM: C = act(A @ W^T + bs) (+R); A,W bf16; out fp32/bf16 ----
template<int ACT, int RES, int OUTF, int OUTB>
__global__ __launch_bounds__(256) void mgemm(const short* __restrict__ A,
    const short* __restrict__ W, const float* __restrict__ bs,
    const float* __restrict__ R, float* __restrict__ Cf, short* __restrict__ Cb,
    int M, int Nn, int K){
  __shared__ __align__(16) short As[64][40], Ws[64][40];
  const int tid = threadIdx.x, lane = tid & 63, wave = tid >> 6;
  const int col = lane & 15, quad = lane >> 4;
  const int wm = wave & 1, wn = wave >> 1;
  const int bm = blockIdx.x * 64, bn = blockIdx.y * 64;
  const f32x4 zero4 = {0.f, 0.f, 0.f, 0.f};
  f32x4 acc[2][2] = {{zero4, zero4}, {zero4, zero4}};
  const int row = tid >> 2, seg = tid & 3;
  for (int k0 = 0; k0 < K; k0 += 32){
    __syncthreads();
    bf16x8 av = (bf16x8)(short)0;
    int gm = bm + row;
    if (gm < M) av = *(const bf16x8*)(A + (long)gm * K + k0 + seg * 8);
    *(bf16x8*)&As[row][seg * 8] = av;
    *(bf16x8*)&Ws[row][seg * 8] = *(const bf16x8*)(W + (long)(bn + row) * K + k0 + seg * 8);
    __syncthreads();
    bf16x8 a0 = *(const bf16x8*)&As[wm * 32 + col][quad * 8];
    bf16x8 a1 = *(const bf16x8*)&As[wm * 32 + 16 + col][quad * 8];
    bf16x8 b0 = *(const bf16x8*)&Ws[wn * 32 + col][quad * 8];
    bf16x8 b1 = *(const bf16x8*)&Ws[wn * 32 + 16 + col][quad * 8];
    acc[0][0] = __builtin_amdgcn_mfma_f32_16x16x32_bf16(a0, b0, acc[0][0], 0, 0, 0);
    acc[0][1] = __builtin_amdgcn_mfma_f32_16x16x32_bf16(a0, b1, acc[0][1], 0, 0, 0);
    acc[1][0] = __builtin_amdgcn_mfma_f32_16x16x32_bf16(a1, b0, acc[1][0], 0, 0, 0);
    acc[1][1] = __builtin_amdgcn_mfma_f32_16x16x32_bf16(a1, b1, acc[1][1], 0, 0, 0);
  }
  #pragma unroll
  for (int i = 0; i < 2; i++)
    #pragma unroll
    for (int j = 0; j < 2; j++)
      #pragma unroll
      for (int r = 0; r < 4; r++){
        int gm = bm + wm * 32 + i * 16 + quad * 4 + r;
        if (gm >= M) continue;
        int gn = bn + wn * 32 + j * 16 + col;
        float v = acc[i][j][r] + bs[gn];
        if (ACT == 1) v = v * 0.5f * (1.0f + erff(v * 0.70710678118654752f));
        if (RES) v += R[(long)gm * Nn + gn];
        if (OUTF) Cf[(long)gm * Nn + gn] = v;
        if (OUTB) Cb[(long)gm * Nn + gn] = (short)f2b(v);
      }
}

// ---- split-K flash attention. grid (65, H, 4); block = 2 waves x 16 rows.
// Quarter qz owns tiles [t0,t1) of the 33 key-tiles. Writes unnormalized
// partials (O, m, l) for a separate merge kernel.
__global__ __launch_bounds__(128) void fattn_k(const short* __restrict__ Qb,
    const short* __restrict__ Kb, const short* __restrict__ Vtg,
    const short* __restrict__ biasb, float* __restrict__ Opart,
    float* __restrict__ Mpart, float* __restrict__ Lpart){
  __shared__ __align__(16) short Ks[64][40];
  __shared__ __align__(16) short Vt[32][72];
  __shared__ __align__(16) short Bs[32][72];
  __shared__ __align__(16) short Ps[2][16][72];

  const int tid = threadIdx.x, wave = tid >> 6, lane = tid & 63;
  const int col = lane & 15, quad = lane >> 4;
  const int h = blockIdx.y, qz = blockIdx.z;
  const int i0b = blockIdx.x * 32;
  const int i0 = i0b + wave * 16;
  const int t0 = qz * 8 + (qz > 0 ? 1 : 0);   // 0,9,17,25
  const int t1 = t0 + (qz == 0 ? 9 : 8);      // 9,17,25,33

  int qrow = min(i0 + col, NF - 1);
  bf16x8 q_frag = *(const bf16x8*)(Qb + (long)qrow * D_ + h * HD_ + quad * 8);

  float mx[4], sm[4];
  f32x4 oacc[2];
  const f32x4 zero4 = {0.f, 0.f, 0.f, 0.f};
  #pragma unroll
  for (int r = 0; r < 4; r++){ mx[r] = -1e30f; sm[r] = 0.f; }
  oacc[0] = zero4; oacc[1] = zero4;

  const float scale = 0.17677669529663687f;  // 1/sqrt(32)

  for (int t = t0; t < t1; t++){
    const int j0 = t * 64;
    __syncthreads();
    // K tile: 64 keys x 32 dims (2 x 128 b128 units)
    #pragma unroll
    for (int it = 0; it < 2; it++){
      int idx = it * 128 + tid;
      int key = idx >> 2, seg = idx & 3;
      int j = j0 + key;
      bf16x8 kv = (bf16x8)(short)0;
      if (j < NF) kv = *(const bf16x8*)(Kb + (long)j * D_ + h * HD_ + seg * 8);
      *(bf16x8*)&Ks[key][seg * 8] = kv;
    }
    // V tile (pre-transposed global): 32 dims x 64 keys
    #pragma unroll
    for (int it = 0; it < 2; it++){
      int idx = it * 128 + tid;
      int d = idx >> 3, seg = idx & 7;
      *(bf16x8*)&Vt[d][seg * 8] =
        *(const bf16x8*)(Vtg + (long)(h * HD_ + d) * BSTRIDE + j0 + seg * 8);
    }
    // bias tile: 32 rows x 64 cols
    #pragma unroll
    for (int it = 0; it < 2; it++){
      int idx = it * 128 + tid;
      int rw = idx >> 3, seg = idx & 7;
      int irow = min(i0b + rw, NF - 1);
      *(bf16x8*)&Bs[rw][seg * 8] =
        *(const bf16x8*)(biasb + ((long)h * NF + irow) * BSTRIDE + j0 + seg * 8);
    }
    __syncthreads();

    f32x4 sacc[4];
    #pragma unroll
    for (int t4 = 0; t4 < 4; t4++){
      bf16x8 kf = *(const bf16x8*)&Ks[t4 * 16 + col][quad * 8];
      sacc[t4] = __builtin_amdgcn_mfma_f32_16x16x32_bf16(q_frag, kf, zero4, 0, 0, 0);
    }

    float lg[4][4];
    #pragma unroll
    for (int r = 0; r < 4; r++){
      #pragma unroll
      for (int t4 = 0; t4 < 4; t4++){
        int j = j0 + t4 * 16 + col;
        float bv = b2f(Bs[wave * 16 + quad * 4 + r][t4 * 16 + col]);
        lg[t4][r] = (j < NF) ? (sacc[t4][r] * scale + bv) : -1e30f;
      }
    }

    #pragma unroll
    for (int r = 0; r < 4; r++){
      float tm = fmaxf(fmaxf(lg[0][r], lg[1][r]), fmaxf(lg[2][r], lg[3][r]));
      #pragma unroll
      for (int o = 1; o < 16; o <<= 1) tm = fmaxf(tm, __shfl_xor(tm, o, 64));
      float nm = fmaxf(mx[r], tm);
      float al = __expf(mx[r] - nm);
      mx[r] = nm;
      float rs = 0.f;
      #pragma unroll
      for (int t4 = 0; t4 < 4; t4++){
        float p = __expf(lg[t4][r] - nm);
        lg[t4][r] = p;
        rs += p;
      }
      #pragma unroll
      for (int o = 1; o < 16; o <<= 1) rs += __shfl_xor(rs, o, 64);
      sm[r] = sm[r] * al + rs;
      oacc[0][r] *= al;
      oacc[1][r] *= al;
    }

    #pragma unroll
    for (int r = 0; r < 4; r++)
      #pragma unroll
      for (int t4 = 0; t4 < 4; t4++)
        Ps[wave][quad * 4 + r][t4 * 16 + col] = (short)f2b(lg[t4][r]);

    #pragma unroll
    for (int ks = 0; ks < 2; ks++){
      bf16x8 af = *(const bf16x8*)&Ps[wave][col][ks * 32 + quad * 8];
      #pragma unroll
      for (int dt = 0; dt < 2; dt++){
        bf16x8 vf = *(const bf16x8*)&Vt[dt * 16 + col][ks * 32 + quad * 8];
        oacc[dt] = __builtin_amdgcn_mfma_f32_16x16x32_bf16(af, vf, oacc[dt], 0, 0, 0);
      }
    }
  }

  #pragma unroll
  for (int r = 0; r < 4; r++){
    int ig = i0 + quad * 4 + r;  // < RPAD always
    long pi = (((long)qz * H_ + h) * RPAD + ig);
    #pragma unroll
    for (int dt = 0; dt < 2; dt++)
      Opart[pi * HD_ + dt * 16 + col] = oacc[dt][r];
    if (col == 0){ Mpart[pi] = mx[r]; Lpart[pi] = sm[r]; }
  }
}

// merge 4 key-quarter partials -> om (bf16). grid (NF), block 256 (h=tid>>5,d=tid&31)
__global__ void attn_merge(const float* __restrict__ Opart,
                           const float* __restrict__ Mp, const float* __restrict__ Lp,
                           short* __restrict__ omb){
  int i = blockIdx.x;
  int h = threadIdx.x >> 5, d = threadIdx.x & 31;
  float m[4], l[4];
  #pragma unroll
  for (int q = 0; q < 4; q++){
    long pi = ((long)q * H_ + h) * RPAD + i;
    m[q] = Mp[pi]; l[q] = Lp[pi];
  }
  float ms = fmaxf(fmaxf(m[0], m[1]), fmaxf(m[2], m[3]));
  float s = 0.f, o = 0.f;
  #pragma unroll
  for (int q = 0; q < 4; q++){
    float w = __expf(m[q] - ms);
    s += w * l[q];
    o += w * Opart[(((long)q * H_ + h) * RPAD + i) * HD_ + d];
  }
  omb[(long)i * D_ + h * HD_ + d] = (short)f2b(o / s);
}

extern "C" void kernel_launch(void* const* d_in, const int* in_sizes, int n_in,
                              void* d_out, int out_size, void* d_ws, size_t ws_size,
                              hipStream_t stream){
  const float* x    = (const float*)d_in[0];
  const float* ea   = (const float*)d_in[1];
  const float* npw  = (const float*)d_in[2];
  const float* npb  = (const float*)d_in[3];
  const float* inE  = (const float*)d_in[4];
  const float* outE = (const float*)d_in[5];
  const float* db   = (const float*)d_in[6];
  const float* epw  = (const float*)d_in[7];
  const float* epb  = (const float*)d_in[8];
  const float* cls  = (const float*)d_in[9];
  const float* qw   = (const float*)d_in[10];
  const float* qb   = (const float*)d_in[11];
  const float* kw   = (const float*)d_in[12];
  const float* kb   = (const float*)d_in[13];
  const float* vw   = (const float*)d_in[14];
  const float* vb   = (const float*)d_in[15];
  const float* ow   = (const float*)d_in[16];
  const float* ob   = (const float*)d_in[17];
  const float* f1w  = (const float*)d_in[18];
  const float* f1b  = (const float*)d_in[19];
  const float* f2w  = (const float*)d_in[20];
  const float* f2bp = (const float*)d_in[21];
  const float* ln1s = (const float*)d_in[22];
  const float* ln1b = (const float*)d_in[23];
  const float* ln2s = (const float*)d_in[24];
  const float* ln2b = (const float*)d_in[25];
  const float* fns  = (const float*)d_in[26];
  const float* fnb  = (const float*)d_in[27];
  const int*   ei   = (const int*)d_in[28];
  const int*   dist = (const int*)d_in[29];

  float* ws = (float*)d_ws;
  long off = 0;
  float* biasf = ws + off; off += (long)H_ * NF * NF;          // fp32 master
  float* h     = ws + off; off += (long)NF * D_;
  float* Opart = ws + off; off += (long)4 * H_ * RPAD * HD_;
  float* Mpart = ws + off; off += (long)4 * H_ * RPAD;
  float* Lpart = ws + off; off += (long)4 * H_ * RPAD;
  short* biasb = (short*)(ws + off); off += ((long)H_ * NF * BSTRIDE + 1) / 2;
  short* hnb   = (short*)(ws + off); off += ((long)NF * D_ + 1) / 2;
  short* QKb   = (short*)(ws + off); off += (long)NF * D_;      // Q then K
  short* Vtg   = (short*)(ws + off); off += ((long)D_ * BSTRIDE + 1) / 2;
  short* omb   = (short*)(ws + off); off += ((long)NF * D_ + 1) / 2;
  short* midb  = (short*)(ws + off); off += ((long)NF * FFN_ + 1) / 2;
  short* wqkv  = (short*)(ws + off); off += ((long)3 * L_ * D_ * D_ + 1) / 2;
  short* owb   = (short*)(ws + off); off += ((long)L_ * D_ * D_ + 1) / 2;
  short* f1wb  = (short*)(ws + off); off += ((long)L_ * FFN_ * D_ + 1) / 2;
  short* f2wb  = (short*)(ws + off); off += ((long)L_ * FFN_ * D_ + 1) / 2;
  int*   ind   = (int*)(ws + off);
  int*   outd  = ind + N_;

  zero_int<<<(2 * N_ + 255) / 256, 256, 0, stream>>>(ind, 2 * N_);
  deg_count<<<(E_ + 255) / 256, 256, 0, stream>>>(ei, ind, outd);
  embed_k<<<NF, D_, 0, stream>>>(x, npw, npb, inE, outE, ind, outd, cls, h);
  long tot = (long)NF * NF;
  bias_fill<<<(int)((tot + 255) / 256), 256, 0, stream>>>(dist, db, biasf);
  edge_bias<<<(E_ + 255) / 256, 256, 0, stream>>>(ea, epw, epb, ei, biasf);
  bias_cvt<<<H_ * NF, 256, 0, stream>>>(biasf, biasb);

  {
    long nw = (long)L_ * D_ * D_;
    int gb = (int)((nw + 255) / 256);
    w2b<<<gb, 256, 0, stream>>>(qw, wqkv, nw, (long)D_ * D_, (long)3 * D_ * D_, 0);
    w2b<<<gb, 256, 0, stream>>>(kw, wqkv, nw, (long)D_ * D_, (long)3 * D_ * D_, (long)D_ * D_);
    w2b<<<gb, 256, 0, stream>>>(vw, wqkv, nw, (long)D_ * D_, (long)3 * D_ * D_, (long)2 * D_ * D_);
    w2b<<<gb, 256, 0, stream>>>(ow, owb, nw, nw, 0, 0);
    long nf = (long)L_ * FFN_ * D_;
    int gf = (int)((nf + 255) / 256);
    w2b<<<gf, 256, 0, stream>>>(f1w, f1wb, nf, nf, 0, 0);
    w2b<<<gf, 256, 0, stream>>>(f2w, f2wb, nf, nf, 0, 0);
  }

  dim3 gQKV((NF + 63) / 64, D_ / 64, 3);
  dim3 gD((NF + 63) / 64, D_ / 64);
  dim3 gF((NF + 63) / 64, FFN_ / 64);
  dim3 gA((NF + 31) / 32, H_, 4);
  for (int l = 0; l < L_; l++){
    ln_k<<<NF, D_, 0, stream>>>(h, ln1s + l * D_, ln1b + l * D_, nullptr, hnb, 0);
    qkv_gemm<<<gQKV, 256, 0, stream>>>(hnb, wqkv, qb + l * D_, kb + l * D_, vb + l * D_,
                                       QKb, Vtg, l);
    fattn_k<<<gA, 128, 0, stream>>>(QKb, QKb + (long)NF * D_, Vtg, biasb,
                                    Opart, Mpart, Lpart);
    attn_merge<<<NF, 256, 0, stream>>>(Opart, Mpart, Lpart, omb);
    mgemm<0,1,1,0><<<gD, 256, 0, stream>>>(omb, owb + (long)l * D_ * D_, ob + l * D_,
                                           h, h, nullptr, NF, D_, D_);
    ln_k<<<NF, D_, 0, stream>>>(h, ln2s + l * D_, ln2b + l * D_, nullptr, hnb, 0);
    mgemm<1,0,0,1><<<gF, 256, 0, stream>>>(hnb, f1wb + (long)l * FFN_ * D_, f1b + l * FFN_,
                                           nullptr, nullptr, midb, NF, FFN_, D_);
    mgemm<0,1,1,0><<<gD, 256, 0, stream>>>(midb, f2wb + (long)l * D_ * FFN_, f2bp + l * D_,
                                           h, h, nullptr, NF, D_, FFN_);
  }
  ln_k<<<NF, D_, 0, stream>>>(h, fns, fnb, (float*)d_out, nullptr, 1);
}

// Round 4
// 695.626 us; speedup vs baseline: 9.6009x; 1.3675x over previous
//
#include <hip/hip_runtime.h>
#include <math.h>

#define N_ 2048
#define NF_IN 64
#define D_ 256
#define H_ 8
#define HD_ 32
#define L_ 6
#define FFN_ 1024
#define E_ 32768
#define EF_ 16
#define NF 2049      // N+1 tokens (CLS at row 0)
#define MAXDEG_ 64
#define BSTRIDE 2112 // padded bias/Vt row stride (33*64, 16B aligned)
#define RPAD 2112    // padded row count for attention partials
#define NSPLIT 8     // key splits for flash attention

typedef __attribute__((ext_vector_type(8))) short bf16x8;
typedef __attribute__((ext_vector_type(4))) float f32x4;

__device__ inline unsigned short f2b(float f){
  union { float f; unsigned u; } v; v.f = f;
  unsigned r = (v.u + 0x7fffu + ((v.u >> 16) & 1u)) >> 16;
  return (unsigned short)r;
}
__device__ inline float b2f(short s){
  union { unsigned u; float f; } v; v.u = ((unsigned)(unsigned short)s) << 16;
  return v.f;
}

__device__ inline void atomic_add_bf16(short* p, float add){
  unsigned* wp = (unsigned*)((size_t)p & ~(size_t)3);
  bool hi = ((size_t)p & 2) != 0;
  unsigned old = *wp, assumed;
  do {
    assumed = old;
    unsigned short cur = hi ? (unsigned short)(assumed >> 16)
                            : (unsigned short)(assumed & 0xffffu);
    float f = b2f((short)cur) + add;
    unsigned short nb = f2b(f);
    unsigned nw = hi ? ((assumed & 0x0000ffffu) | ((unsigned)nb << 16))
                     : ((assumed & 0xffff0000u) | (unsigned)nb);
    old = atomicCAS(wp, assumed, nw);
  } while (old != assumed);
}

__device__ inline float wred_sum(float v){
  #pragma unroll
  for (int o = 32; o > 0; o >>= 1) v += __shfl_down(v, o, 64);
  return v;
}

__global__ void zero_int(int* p, int n){
  int i = blockIdx.x * blockDim.x + threadIdx.x;
  if (i < n) p[i] = 0;
}

__global__ void deg_count(const int* __restrict__ ei, int* __restrict__ ind,
                          int* __restrict__ outd){
  int e = blockIdx.x * blockDim.x + threadIdx.x;
  if (e >= E_) return;
  atomicAdd(&outd[ei[e]], 1);
  atomicAdd(&ind[ei[E_ + e]], 1);
}

__global__ void embed_k(const float* __restrict__ x, const float* __restrict__ W,
                        const float* __restrict__ b, const float* __restrict__ inE,
                        const float* __restrict__ outE, const int* __restrict__ ind,
                        const int* __restrict__ outd, const float* __restrict__ cls,
                        float* __restrict__ h){
  int i = blockIdx.x, d = threadIdx.x;
  if (i == 0){ h[d] = cls[d]; return; }
  int n = i - 1;
  const float4* xr = (const float4*)(x + (long)n * NF_IN);
  const float4* wr = (const float4*)(W + (long)d * NF_IN);
  float acc = b[d];
  #pragma unroll
  for (int k = 0; k < NF_IN / 4; k++){
    float4 a = xr[k], w = wr[k];
    acc += a.x * w.x + a.y * w.y + a.z * w.z + a.w * w.w;
  }
  int id = min(ind[n], MAXDEG_), od = min(outd[n], MAXDEG_);
  acc += inE[(long)id * D_ + d] + outE[(long)od * D_ + d];
  h[(long)i * D_ + d] = acc;
}

// bias written directly as padded bf16 [h][i][j]; grid NF (one block per row i)
__global__ void bias_fill(const int* __restrict__ dist, const float* __restrict__ db,
                          short* __restrict__ bb){
  __shared__ float lutS[10][H_];
  int i = blockIdx.x;
  if (threadIdx.x < 80) ((float*)lutS)[threadIdx.x] = db[threadIdx.x];
  __syncthreads();
  for (int u = threadIdx.x; u < BSTRIDE / 8; u += 256){
    int dp[8];
    #pragma unroll
    for (int k = 0; k < 8; k++){
      int j = u * 8 + k;
      int d = 0;
      if (i > 0 && j > 0 && j < NF){
        int dv = dist[(long)(i - 1) * N_ + (j - 1)];
        d = max(0, min(dv, 9));
      }
      dp[k] = (j < NF) ? d : -1;
    }
    #pragma unroll
    for (int h = 0; h < H_; h++){
      short s[8];
      #pragma unroll
      for (int k = 0; k < 8; k++)
        s[k] = (dp[k] >= 0) ? (short)f2b(lutS[dp[k]][h]) : (short)0;
      *(bf16x8*)(bb + ((long)h * NF + i) * BSTRIDE + u * 8) = *(bf16x8*)s;
    }
  }
}

// sparse edge-feature bias: CAS-based bf16 add into the dense bias planes
__global__ void edge_bias(const float* __restrict__ ea, const float* __restrict__ W,
                          const float* __restrict__ b, const int* __restrict__ ei,
                          short* __restrict__ bb){
  int e = blockIdx.x * blockDim.x + threadIdx.x;
  if (e >= E_) return;
  float a[EF_];
  #pragma unroll
  for (int k = 0; k < EF_; k++) a[k] = ea[(long)e * EF_ + k];
  int src = ei[e], dst = ei[E_ + e];
  #pragma unroll
  for (int h = 0; h < H_; h++){
    float p = b[h];
    #pragma unroll
    for (int k = 0; k < EF_; k++) p += a[k] * W[h * EF_ + k];
    atomic_add_bf16(bb + ((long)h * NF + src + 1) * BSTRIDE + (dst + 1), p);
  }
}

__global__ void w2b(const float* __restrict__ src, short* __restrict__ dst,
                    long n, long per, long ostride, long ooff){
  long i = (long)blockIdx.x * 256 + threadIdx.x;
  if (i >= n) return;
  long l = i / per, r = i - l * per;
  dst[l * ostride + ooff + r] = (short)f2b(src[i]);
}

__global__ void ln_k(const float* __restrict__ in, const float* __restrict__ s,
                     const float* __restrict__ b, float* __restrict__ outf,
                     short* __restrict__ outb, int dup0){
  __shared__ float r1[4], r2[4];
  int i = blockIdx.x, d = threadIdx.x;
  float v = in[(long)i * D_ + d];
  float s1 = wred_sum(v), s2 = wred_sum(v * v);
  if ((d & 63) == 0){ r1[d >> 6] = s1; r2[d >> 6] = s2; }
  __syncthreads();
  float S1 = r1[0] + r1[1] + r1[2] + r1[3];
  float S2 = r2[0] + r2[1] + r2[2] + r2[3];
  float m = S1 * (1.0f / D_);
  float var = S2 * (1.0f / D_) - m * m;
  float y = (v - m) * rsqrtf(var + 1e-5f) * s[d] + b[d];
  if (outf){
    outf[(long)i * D_ + d] = y;
    if (dup0 && i == 0) outf[(long)NF * D_ + d] = y;
  }
  if (outb) outb[(long)i * D_ + d] = (short)f2b(y);
}

// ---- fused QKV MFMA GEMM: grid (33, 4, 3); z selects weight/bias/output ----
__global__ __launch_bounds__(256) void qkv_gemm(const short* __restrict__ A,
    const short* __restrict__ Wall, const float* __restrict__ qb,
    const float* __restrict__ kb, const float* __restrict__ vb,
    short* __restrict__ QKb, short* __restrict__ Vtg, int l){
  const int z = blockIdx.z;
  const short* W = Wall + ((long)(l * 3 + z)) * D_ * D_;
  const float* bsp = (z == 0) ? qb : (z == 1) ? kb : vb;
  __shared__ __align__(16) short As[64][40], Ws[64][40];
  const int tid = threadIdx.x, lane = tid & 63, wave = tid >> 6;
  const int col = lane & 15, quad = lane >> 4;
  const int wm = wave & 1, wn = wave >> 1;
  const int bm = blockIdx.x * 64, bn = blockIdx.y * 64;
  const f32x4 zero4 = {0.f, 0.f, 0.f, 0.f};
  f32x4 acc[2][2] = {{zero4, zero4}, {zero4, zero4}};
  const int row = tid >> 2, seg = tid & 3;
  for (int k0 = 0; k0 < D_; k0 += 32){
    __syncthreads();
    bf16x8 av = (bf16x8)(short)0;
    int gm = bm + row;
    if (gm < NF) av = *(const bf16x8*)(A + (long)gm * D_ + k0 + seg * 8);
    *(bf16x8*)&As[row][seg * 8] = av;
    *(bf16x8*)&Ws[row][seg * 8] = *(const bf16x8*)(W + (long)(bn + row) * D_ + k0 + seg * 8);
    __syncthreads();
    bf16x8 a0 = *(const bf16x8*)&As[wm * 32 + col][quad * 8];
    bf16x8 a1 = *(const bf16x8*)&As[wm * 32 + 16 + col][quad * 8];
    bf16x8 b0 = *(const bf16x8*)&Ws[wn * 32 + col][quad * 8];
    bf16x8 b1 = *(const bf16x8*)&Ws[wn * 32 + 16 + col][quad * 8];
    acc[0][0] = __builtin_amdgcn_mfma_f32_16x16x32_bf16(a0, b0, acc[0][0], 0, 0, 0);
    acc[0][1] = __builtin_amdgcn_mfma_f32_16x16x32_bf16(a0, b1, acc[0][1], 0, 0, 0);
    acc[1][0] = __builtin_amdgcn_mfma_f32_16x16x32_bf16(a1, b0, acc[1][0], 0, 0, 0);
    acc[1][1] = __builtin_amdgcn_mfma_f32_16x16x32_bf16(a1, b1, acc[1][1], 0, 0, 0);
  }
  #pragma unroll
  for (int i = 0; i < 2; i++)
    #pragma unroll
    for (int j = 0; j < 2; j++)
      #pragma unroll
      for (int r = 0; r < 4; r++){
        int gm = bm + wm * 32 + i * 16 + quad * 4 + r;
        if (gm >= NF) continue;
        int gn = bn + wn * 32 + j * 16 + col;
        float v = acc[i][j][r] + bsp[gn];
        if (z < 2) QKb[(long)z * NF * D_ + (long)gm * D_ + gn] = (short)f2b(v);
        else       Vtg[(long)gn * BSTRIDE + gm] = (short)f2b(v);
      }
}

// ---- generic MFMA GEMM; ATOM=1: split-K partial atomically added into Cf ----
template<int ACT, int RES, int OUTF, int OUTB, int ATOM>
__global__ __launch_bounds__(256) void mgemm(const short* __restrict__ A,
    const short* __restrict__ W, const float* __restrict__ bs,
    const float* __restrict__ R, float* __restrict__ Cf, short* __restrict__ Cb,
    int M, int Nn, int Kc, int Kstride){
  __shared__ __align__(16) short As[64][40], Ws[64][40];
  const int tid = threadIdx.x, lane = tid & 63, wave = tid >> 6;
  const int col = lane & 15, quad = lane >> 4;
  const int wm = wave & 1, wn = wave >> 1;
  const int bm = blockIdx.x * 64, bn = blockIdx.y * 64;
  const int koff = blockIdx.z * Kc;
  const f32x4 zero4 = {0.f, 0.f, 0.f, 0.f};
  f32x4 acc[2][2] = {{zero4, zero4}, {zero4, zero4}};
  const int row = tid >> 2, seg = tid & 3;
  for (int k0 = 0; k0 < Kc; k0 += 32){
    __syncthreads();
    bf16x8 av = (bf16x8)(short)0;
    int gm = bm + row;
    if (gm < M) av = *(const bf16x8*)(A + (long)gm * Kstride + koff + k0 + seg * 8);
    *(bf16x8*)&As[row][seg * 8] = av;
    *(bf16x8*)&Ws[row][seg * 8] =
      *(const bf16x8*)(W + (long)(bn + row) * Kstride + koff + k0 + seg * 8);
    __syncthreads();
    bf16x8 a0 = *(const bf16x8*)&As[wm * 32 + col][quad * 8];
    bf16x8 a1 = *(const bf16x8*)&As[wm * 32 + 16 + col][quad * 8];
    bf16x8 b0 = *(const bf16x8*)&Ws[wn * 32 + col][quad * 8];
    bf16x8 b1 = *(const bf16x8*)&Ws[wn * 32 + 16 + col][quad * 8];
    acc[0][0] = __builtin_amdgcn_mfma_f32_16x16x32_bf16(a0, b0, acc[0][0], 0, 0, 0);
    acc[0][1] = __builtin_amdgcn_mfma_f32_16x16x32_bf16(a0, b1, acc[0][1], 0, 0, 0);
    acc[1][0] = __builtin_amdgcn_mfma_f32_16x16x32_bf16(a1, b0, acc[1][0], 0, 0, 0);
    acc[1][1] = __builtin_amdgcn_mfma_f32_16x16x32_bf16(a1, b1, acc[1][1], 0, 0, 0);
  }
  #pragma unroll
  for (int i = 0; i < 2; i++)
    #pragma unroll
    for (int j = 0; j < 2; j++)
      #pragma unroll
      for (int r = 0; r < 4; r++){
        int gm = bm + wm * 32 + i * 16 + quad * 4 + r;
        if (gm >= M) continue;
        int gn = bn + wn * 32 + j * 16 + col;
        if (ATOM){
          float v = acc[i][j][r] + (blockIdx.z == 0 ? bs[gn] : 0.f);
          atomicAdd(&Cf[(long)gm * Nn + gn], v);
        } else {
          float v = acc[i][j][r] + bs[gn];
          if (ACT == 1) v = v * 0.5f * (1.0f + erff(v * 0.70710678118654752f));
          if (RES) v += R[(long)gm * Nn + gn];
          if (OUTF) Cf[(long)gm * Nn + gn] = v;
          if (OUTB) Cb[(long)gm * Nn + gn] = (short)f2b(v);
        }
      }
}

// ---- flash attention, fixed-shift softmax (logits provably tiny => exp(l)
// directly; softmax shift-invariance makes this exact). grid (33, H, NSPLIT);
// block = 4 waves x 16 rows = 64 rows. Bias LDS buffer doubles as P buffer
// (wave-private: each (row,col) element is read & written by the same lane).
__global__ __launch_bounds__(256) void fattn_k(const short* __restrict__ Qb,
    const short* __restrict__ Kb, const short* __restrict__ Vtg,
    const short* __restrict__ biasb, float* __restrict__ Opart,
    float* __restrict__ Lpart){
  __shared__ __align__(16) short Ks[64][40];
  __shared__ __align__(16) short Vt[32][72];
  __shared__ __align__(16) short PB[4][16][72];

  const int tid = threadIdx.x, wave = tid >> 6, lane = tid & 63;
  const int col = lane & 15, quad = lane >> 4;
  const int h = blockIdx.y, qz = blockIdx.z;
  const int i0b = blockIdx.x * 64;
  const int i0 = i0b + wave * 16;
  const int t0 = (qz == 0) ? 0 : 5 + 4 * (qz - 1);   // 0,5,9,...,29
  const int t1 = t0 + ((qz == 0) ? 5 : 4);           // 33 tiles total

  int qrow = min(i0 + col, NF - 1);
  bf16x8 qf = *(const bf16x8*)(Qb + (long)qrow * D_ + h * HD_ + quad * 8);

  f32x4 oacc0 = {0.f, 0.f, 0.f, 0.f}, oacc1 = {0.f, 0.f, 0.f, 0.f};
  float rs[4] = {0.f, 0.f, 0.f, 0.f};
  const f32x4 zero4 = {0.f, 0.f, 0.f, 0.f};
  const float scale = 0.17677669529663687f;  // 1/sqrt(32)

  for (int t = t0; t < t1; t++){
    const int j0 = t * 64;
    __syncthreads();
    { // K tile: 64 keys x 32 dims
      int key = tid >> 2, seg = tid & 3;
      int j = j0 + key;
      bf16x8 kv = (bf16x8)(short)0;
      if (j < NF) kv = *(const bf16x8*)(Kb + (long)j * D_ + h * HD_ + seg * 8);
      *(bf16x8*)&Ks[key][seg * 8] = kv;
    }
    { // V tile (pre-transposed): 32 dims x 64 keys
      int d = tid >> 3, seg = tid & 7;
      *(bf16x8*)&Vt[d][seg * 8] =
        *(const bf16x8*)(Vtg + (long)(h * HD_ + d) * BSTRIDE + j0 + seg * 8);
    }
    #pragma unroll
    for (int it = 0; it < 2; it++){ // per-wave bias tile: 16 rows x 64 cols
      int idx = it * 64 + lane;
      int rw = idx >> 3, seg = idx & 7;
      int irow = min(i0b + wave * 16 + rw, NF - 1);
      *(bf16x8*)&PB[wave][rw][seg * 8] =
        *(const bf16x8*)(biasb + ((long)h * NF + irow) * BSTRIDE + j0 + seg * 8);
    }
    __syncthreads();

    f32x4 sacc[4];
    #pragma unroll
    for (int t4 = 0; t4 < 4; t4++){
      bf16x8 kf = *(const bf16x8*)&Ks[t4 * 16 + col][quad * 8];
      sacc[t4] = __builtin_amdgcn_mfma_f32_16x16x32_bf16(qf, kf, zero4, 0, 0, 0);
    }

    const bool tail = (j0 + 64 > NF);
    #pragma unroll
    for (int r = 0; r < 4; r++){
      #pragma unroll
      for (int t4 = 0; t4 < 4; t4++){
        float bv = b2f(PB[wave][quad * 4 + r][t4 * 16 + col]);
        float p = __expf(sacc[t4][r] * scale + bv);
        if (tail && (j0 + t4 * 16 + col >= NF)) p = 0.f;
        rs[r] += p;
        PB[wave][quad * 4 + r][t4 * 16 + col] = (short)f2b(p);
      }
    }

    #pragma unroll
    for (int ks = 0; ks < 2; ks++){
      bf16x8 af = *(const bf16x8*)&PB[wave][col][ks * 32 + quad * 8];
      bf16x8 v0 = *(const bf16x8*)&Vt[col][ks * 32 + quad * 8];
      bf16x8 v1 = *(const bf16x8*)&Vt[16 + col][ks * 32 + quad * 8];
      oacc0 = __builtin_amdgcn_mfma_f32_16x16x32_bf16(af, v0, oacc0, 0, 0, 0);
      oacc1 = __builtin_amdgcn_mfma_f32_16x16x32_bf16(af, v1, oacc1, 0, 0, 0);
    }
  }

  #pragma unroll
  for (int r = 0; r < 4; r++){
    #pragma unroll
    for (int o = 1; o < 16; o <<= 1) rs[r] += __shfl_xor(rs[r], o, 64);
  }
  long pi = ((long)qz * H_ + h) * RPAD + i0 + quad * 4;
  #pragma unroll
  for (int r = 0; r < 4; r++){
    Opart[(pi + r) * HD_ + col] = oacc0[r];
    Opart[(pi + r) * HD_ + 16 + col] = oacc1[r];
    if (col == 0) Lpart[pi + r] = rs[r];
  }
}

// merge NSPLIT partials: om = sum(O_q) / sum(L_q)
__global__ void attn_merge(const float* __restrict__ Op, const float* __restrict__ Lp,
                           short* __restrict__ omb){
  int i = blockIdx.x;
  int h = threadIdx.x >> 5, d = threadIdx.x & 31;
  float s = 0.f, o = 0.f;
  #pragma unroll
  for (int q = 0; q < NSPLIT; q++){
    long pi = ((long)q * H_ + h) * RPAD + i;
    s += Lp[pi];
    o += Op[pi * HD_ + d];
  }
  omb[(long)i * D_ + h * HD_ + d] = (short)f2b(o / s);
}

extern "C" void kernel_launch(void* const* d_in, const int* in_sizes, int n_in,
                              void* d_out, int out_size, void* d_ws, size_t ws_size,
                              hipStream_t stream){
  const float* x    = (const float*)d_in[0];
  const float* ea   = (const float*)d_in[1];
  const float* npw  = (const float*)d_in[2];
  const float* npb  = (const float*)d_in[3];
  const float* inE  = (const float*)d_in[4];
  const float* outE = (const float*)d_in[5];
  const float* db   = (const float*)d_in[6];
  const float* epw  = (const float*)d_in[7];
  const float* epb  = (const float*)d_in[8];
  const float* cls  = (const float*)d_in[9];
  const float* qw   = (const float*)d_in[10];
  const float* qb   = (const float*)d_in[11];
  const float* kw   = (const float*)d_in[12];
  const float* kb   = (const float*)d_in[13];
  const float* vw   = (const float*)d_in[14];
  const float* vb   = (const float*)d_in[15];
  const float* ow   = (const float*)d_in[16];
  const float* ob   = (const float*)d_in[17];
  const float* f1w  = (const float*)d_in[18];
  const float* f1b  = (const float*)d_in[19];
  const float* f2w  = (const float*)d_in[20];
  const float* f2bp = (const float*)d_in[21];
  const float* ln1s = (const float*)d_in[22];
  const float* ln1b = (const float*)d_in[23];
  const float* ln2s = (const float*)d_in[24];
  const float* ln2b = (const float*)d_in[25];
  const float* fns  = (const float*)d_in[26];
  const float* fnb  = (const float*)d_in[27];
  const int*   ei   = (const int*)d_in[28];
  const int*   dist = (const int*)d_in[29];

  float* ws = (float*)d_ws;
  long off = 0;
  float* h     = ws + off; off += (long)NF * D_;
  float* Opart = ws + off; off += (long)NSPLIT * H_ * RPAD * HD_;
  float* Lpart = ws + off; off += (long)NSPLIT * H_ * RPAD;
  short* biasb = (short*)(ws + off); off += ((long)H_ * NF * BSTRIDE + 1) / 2;
  short* hnb   = (short*)(ws + off); off += ((long)NF * D_ + 1) / 2;
  short* QKb   = (short*)(ws + off); off += (long)NF * D_;      // Q then K
  short* Vtg   = (short*)(ws + off); off += ((long)D_ * BSTRIDE + 1) / 2;
  short* omb   = (short*)(ws + off); off += ((long)NF * D_ + 1) / 2;
  short* midb  = (short*)(ws + off); off += ((long)NF * FFN_ + 1) / 2;
  short* wqkv  = (short*)(ws + off); off += ((long)3 * L_ * D_ * D_ + 1) / 2;
  short* owb   = (short*)(ws + off); off += ((long)L_ * D_ * D_ + 1) / 2;
  short* f1wb  = (short*)(ws + off); off += ((long)L_ * FFN_ * D_ + 1) / 2;
  short* f2wb  = (short*)(ws + off); off += ((long)L_ * FFN_ * D_ + 1) / 2;
  int*   ind   = (int*)(ws + off);
  int*   outd  = ind + N_;

  zero_int<<<(2 * N_ + 255) / 256, 256, 0, stream>>>(ind, 2 * N_);
  deg_count<<<(E_ + 255) / 256, 256, 0, stream>>>(ei, ind, outd);
  embed_k<<<NF, D_, 0, stream>>>(x, npw, npb, inE, outE, ind, outd, cls, h);
  bias_fill<<<NF, 256, 0, stream>>>(dist, db, biasb);
  edge_bias<<<(E_ + 255) / 256, 256, 0, stream>>>(ea, epw, epb, ei, biasb);

  {
    long nw = (long)L_ * D_ * D_;
    int gb = (int)((nw + 255) / 256);
    w2b<<<gb, 256, 0, stream>>>(qw, wqkv, nw, (long)D_ * D_, (long)3 * D_ * D_, 0);
    w2b<<<gb, 256, 0, stream>>>(kw, wqkv, nw, (long)D_ * D_, (long)3 * D_ * D_, (long)D_ * D_);
    w2b<<<gb, 256, 0, stream>>>(vw, wqkv, nw, (long)D_ * D_, (long)3 * D_ * D_, (long)2 * D_ * D_);
    w2b<<<gb, 256, 0, stream>>>(ow, owb, nw, nw, 0, 0);
    long nf = (long)L_ * FFN_ * D_;
    int gf = (int)((nf + 255) / 256);
    w2b<<<gf, 256, 0, stream>>>(f1w, f1wb, nf, nf, 0, 0);
    w2b<<<gf, 256, 0, stream>>>(f2w, f2wb, nf, nf, 0, 0);
  }

  dim3 gQKV((NF + 63) / 64, D_ / 64, 3);
  dim3 gO((NF + 63) / 64, D_ / 64, 2);
  dim3 gF((NF + 63) / 64, FFN_ / 64, 1);
  dim3 gF2((NF + 63) / 64, D_ / 64, 4);
  dim3 gA((NF + 63) / 64, H_, NSPLIT);
  for (int l = 0; l < L_; l++){
    ln_k<<<NF, D_, 0, stream>>>(h, ln1s + l * D_, ln1b + l * D_, nullptr, hnb, 0);
    qkv_gemm<<<gQKV, 256, 0, stream>>>(hnb, wqkv, qb + l * D_, kb + l * D_, vb + l * D_,
                                       QKb, Vtg, l);
    fattn_k<<<gA, 256, 0, stream>>>(QKb, QKb + (long)NF * D_, Vtg, biasb, Opart, Lpart);
    attn_merge<<<NF, 256, 0, stream>>>(Opart, Lpart, omb);
    mgemm<0,0,0,0,1><<<gO, 256, 0, stream>>>(omb, owb + (long)l * D_ * D_, ob + l * D_,
                                             nullptr, h, nullptr, NF, D_, 128, D_);
    ln_k<<<NF, D_, 0, stream>>>(h, ln2s + l * D_, ln2b + l * D_, nullptr, hnb, 0);
    mgemm<1,0,0,1,0><<<gF, 256, 0, stream>>>(hnb, f1wb + (long)l * FFN_ * D_, f1b + l * FFN_,
                                             nullptr, nullptr, midb, NF, FFN_, D_, D_);
    mgemm<0,0,0,0,1><<<gF2, 256, 0, stream>>>(midb, f2wb + (long)l * FFN_ * D_, f2bp + l * D_,
                                              nullptr, h, nullptr, NF, D_, 256, FFN_);
  }
  ln_k<<<NF, D_, 0, stream>>>(h, fns, fnb, (float*)d_out, nullptr, 1);
}